// Round 9
// baseline (216.442 us; speedup 1.0000x reference)
//
#include <hip/hip_runtime.h>
#include <stdint.h>

// EdgeNetwork, round 14: NO INTERMEDIATE — MFMA msgs + fire-and-forget atomics.
// r13 post-mortem: accum 80us = 1-chain/wave latency (orow->gather->bpermute,
// 0 MFMA, 663GB/s); reconciled totals show scatter ~45us (640k random 8B
// stores = RFO, the r10 lesson repeated). Pattern across r3-r13: ANY per-edge
// intermediate keyed by dst costs 40-80us (RFO-scatter or gather-latency),
// wherever we move it. out is 1.28MB = L2-RESIDENT -> skip ranking/binning/
// msgs/reduce entirely: r8's proven MFMA compute + 4 no-return f32 atomicAdds
// per lane straight into out[dst]. No-return atomics never enter the wave's
// dependency chain (r4's regression was a RANKING atomic whose RESULT gated
// the store). 10.2M lane-atomics to 320k L2 addrs ~ 10-20us TCC work,
// overlapped with streaming compute (46MB coalesced). 2 dispatches, 0 ws.
// History: r5 148.8 -> r6 147.3 -> r7 136.5 -> r8 133.0 -> r9 138 -> r10 154
// -> r11 202 -> r12 133.5 (3 dispatches) -> r13 191 (latency+RFO diagnosed).

constexpr int DIM = 16;
constexpr int GPW = 4;      // 16-edge groups per wave, fully unrolled

using frag_ab = __attribute__((ext_vector_type(8))) short;   // 8 bf16
using frag_cd = __attribute__((ext_vector_type(4))) float;   // 4 f32
union ABPack { frag_ab f; uint32_t u[4]; };

__device__ __forceinline__ uint32_t pack_bf16_2(float lo, float hi) {
    // one v_perm_b32: truncate-to-bf16 pair, lo in low 16 bits
    return __builtin_amdgcn_perm(__float_as_uint(hi), __float_as_uint(lo), 0x07060302u);
}

// ---- single pass: MFMA message + 4 fire-and-forget f32 atomics per lane
__global__ __launch_bounds__(256) void msg_atomic_kernel(
    const float* __restrict__ atom, const float* __restrict__ bond,
    const int*   __restrict__ pair, const float* __restrict__ kern,
    const float* __restrict__ bias, float* __restrict__ out,
    int n_edges, int n_groups)
{
    const int wave = (int)((blockIdx.x * blockDim.x + threadIdx.x) >> 6);
    const int lane = threadIdx.x & 63;
    const int g0 = wave * GPW;
    if (g0 >= n_groups) return;

    const int col  = lane & 15;        // A(W): output row i | B(Z): edge e | D: col e
    const int quad = lane >> 4;        // 0..3
    const int hb   = quad >> 1;        // k parity within chunk (0/1, fixed per lane)
    const int j0   = (quad & 1) * 8;   // neigh sub-range (for W/bias frag layout)

    // P1: pair loads (quad0 lanes only)
    int  ec_[GPW];
    int2 pr_[GPW];
#pragma unroll
    for (int u = 0; u < GPW; ++u) {
        const int e = ((g0 + u) << 4) + col;
        ec_[u] = min(e, n_edges - 1);
        pr_[u] = make_int2(0, 0);
        if (quad == 0) pr_[u] = ((const int2*)pair)[ec_[u]];
    }

    // W fragments (L1-hot broadcast; overlaps P1 latency)
    frag_ab wfrag[8];
#pragma unroll
    for (int c = 0; c < 8; ++c) {
        const float* wp = kern + (2 * c + hb) * 256 + col * 16 + j0;
        float4 w0 = *(const float4*)wp;
        float4 w1 = *(const float4*)(wp + 4);
        ABPack p;
        p.u[0] = pack_bf16_2(w0.x, w0.y);
        p.u[1] = pack_bf16_2(w0.z, w0.w);
        p.u[2] = pack_bf16_2(w1.x, w1.y);
        p.u[3] = pack_bf16_2(w1.z, w1.w);
        wfrag[c] = p.f;
    }
    frag_ab bias_a;
    {
        ABPack p; p.u[0] = p.u[1] = p.u[2] = p.u[3] = 0;
        if (hb == 0) {
            const float* bp2 = bias + col * 16 + j0;
            float4 w0 = *(const float4*)bp2;
            float4 w1 = *(const float4*)(bp2 + 4);
            p.u[0] = pack_bf16_2(w0.x, w0.y);
            p.u[1] = pack_bf16_2(w0.z, w0.w);
            p.u[2] = pack_bf16_2(w1.x, w1.y);
            p.u[3] = pack_bf16_2(w1.z, w1.w);
        }
        bias_a = p.f;
    }

    // src broadcast
    int src_[GPW];
#pragma unroll
    for (int u = 0; u < GPW; ++u) src_[u] = __shfl(pr_[u].y, col, 64);

    // P2: dedup gathers. atom: chunk cq=[0,2,1,3][quad] of src row (one xor32
    // restores both halves). bond: chunk `quad` -> 1KB contiguous per group.
    const int cq = ((quad & 1) << 1) | (quad >> 1);
    float4 am_[GPW], bm_[GPW];
#pragma unroll
    for (int u = 0; u < GPW; ++u) {
        am_[u] = *(const float4*)(atom + (size_t)src_[u] * DIM + cq * 4);
        bm_[u] = *(const float4*)(bond + (size_t)ec_[u] * DIM + quad * 4);
    }

    // P4: per group: redistribute + pack + MFMA + atomic scatter-add
#pragma unroll
    for (int u = 0; u < GPW; ++u) {
        // atom exchange: xor32 swaps chunk pairs (0<->1, 2<->3)
        float4 am = am_[u];
        float4 ao;
        ao.x = __shfl_xor(am.x, 32); ao.y = __shfl_xor(am.y, 32);
        ao.z = __shfl_xor(am.z, 32); ao.w = __shfl_xor(am.w, 32);
        float nb[8];
        nb[0] = quad < 2 ? am.x : ao.x;  nb[1] = quad < 2 ? am.y : ao.y;
        nb[2] = quad < 2 ? am.z : ao.z;  nb[3] = quad < 2 ? am.w : ao.w;
        nb[4] = quad < 2 ? ao.x : am.x;  nb[5] = quad < 2 ? ao.y : am.y;
        nb[6] = quad < 2 ? ao.z : am.z;  nb[7] = quad < 2 ? ao.w : am.w;

        // bond butterfly: stage1 xor16 pairs chunks within a half
        float4 bm = bm_[u];
        float4 bo;
        bo.x = __shfl_xor(bm.x, 16); bo.y = __shfl_xor(bm.y, 16);
        bo.z = __shfl_xor(bm.z, 16); bo.w = __shfl_xor(bm.w, 16);
        float4 cA, cB;   // even / odd chunk of this lane's half
        cA.x = (quad & 1) ? bo.x : bm.x; cA.y = (quad & 1) ? bo.y : bm.y;
        cA.z = (quad & 1) ? bo.z : bm.z; cA.w = (quad & 1) ? bo.w : bm.w;
        cB.x = (quad & 1) ? bm.x : bo.x; cB.y = (quad & 1) ? bm.y : bo.y;
        cB.z = (quad & 1) ? bm.z : bo.z; cB.w = (quad & 1) ? bm.w : bo.w;
        float s0 = hb ? cA.y : cA.x,  s1 = hb ? cA.w : cA.z;
        float s2 = hb ? cB.y : cB.x,  s3 = hb ? cB.w : cB.z;
        float g0v = hb ? cA.x : cA.y, g1v = hb ? cA.z : cA.w;
        float g2v = hb ? cB.x : cB.y, g3v = hb ? cB.z : cB.w;
        float t0 = __shfl_xor(g0v, 32), t1 = __shfl_xor(g1v, 32);
        float t2 = __shfl_xor(g2v, 32), t3 = __shfl_xor(g3v, 32);
        float bks[8];
        bks[0] = quad < 2 ? s0 : t0;  bks[1] = quad < 2 ? s1 : t1;
        bks[2] = quad < 2 ? s2 : t2;  bks[3] = quad < 2 ? s3 : t3;
        bks[4] = quad < 2 ? t0 : s0;  bks[5] = quad < 2 ? t1 : s1;
        bks[6] = quad < 2 ? t2 : s2;  bks[7] = quad < 2 ? t3 : s3;

        // dual accumulators (even/odd k-chunk) to halve serial MFMA latency
        frag_cd acc0 = {0.f, 0.f, 0.f, 0.f};
        frag_cd acc1 = {0.f, 0.f, 0.f, 0.f};
#pragma unroll
        for (int c = 0; c < 8; ++c) {
            const float bk = bks[c];
            ABPack z;
            z.u[0] = pack_bf16_2(bk * nb[0], bk * nb[1]);
            z.u[1] = pack_bf16_2(bk * nb[2], bk * nb[3]);
            z.u[2] = pack_bf16_2(bk * nb[4], bk * nb[5]);
            z.u[3] = pack_bf16_2(bk * nb[6], bk * nb[7]);
            if (c & 1)
                acc1 = __builtin_amdgcn_mfma_f32_16x16x32_bf16(wfrag[c], z.f, acc1, 0, 0, 0);
            else
                acc0 = __builtin_amdgcn_mfma_f32_16x16x32_bf16(wfrag[c], z.f, acc0, 0, 0, 0);
        }
        { // bias chunk (k<16 half only)
            ABPack z; z.u[0] = z.u[1] = z.u[2] = z.u[3] = 0;
            if (hb == 0) {
                z.u[0] = pack_bf16_2(nb[0], nb[1]);
                z.u[1] = pack_bf16_2(nb[2], nb[3]);
                z.u[2] = pack_bf16_2(nb[4], nb[5]);
                z.u[3] = pack_bf16_2(nb[6], nb[7]);
            }
            acc1 = __builtin_amdgcn_mfma_f32_16x16x32_bf16(bias_a, z.f, acc1, 0, 0, 0);
        }
        frag_cd acc = acc0 + acc1;

        // D^T: lane (quad,col) holds msgs[e=col][i=quad*4 .. +3].
        // dst broadcast from quad0 lane `col`, then 4 NO-RETURN f32 atomics
        // into the L2-resident out row. Never enters the dependency chain.
        const int  dstb = __shfl(pr_[u].x, col, 64);
        const int  e    = ((g0 + u) << 4) + col;
        if (e < n_edges) {
            float* orow = out + (size_t)dstb * DIM + quad * 4;
            atomicAdd(orow + 0, acc[0]);
            atomicAdd(orow + 1, acc[1]);
            atomicAdd(orow + 2, acc[2]);
            atomicAdd(orow + 3, acc[3]);
        }
    }
}

extern "C" void kernel_launch(void* const* d_in, const int* in_sizes, int n_in,
                              void* d_out, int out_size, void* d_ws, size_t ws_size,
                              hipStream_t stream)
{
    const float* atom = (const float*)d_in[0];   // (20000,16) f32
    const float* bond = (const float*)d_in[1];   // (640000,16) f32
    const int*   pair = (const int*)d_in[2];     // (640000,2) i32 [dst, src]
    const float* kern = (const float*)d_in[3];   // (16,256) f32
    const float* bias = (const float*)d_in[4];   // (256,) f32
    float*       out  = (float*)d_out;           // (20000,16) f32

    const int n_edges = in_sizes[1] / DIM;       // 640000

    const int threads  = 256;
    const int n_groups = (n_edges + 15) / 16;                      // 40000
    const int waves    = (n_groups + GPW - 1) / GPW;               // 10000
    const int mblocks  = (waves * 64 + threads - 1) / threads;     // 2500

    // zero the 1.28MB output (L2-resident accumulation target)
    hipMemsetAsync(out, 0, (size_t)out_size * sizeof(float), stream);

    msg_atomic_kernel<<<mblocks, threads, 0, stream>>>(
        atom, bond, pair, kern, bias, out, n_edges, n_groups);
}